// Round 15
// baseline (353.774 us; speedup 1.0000x reference)
//
#include <hip/hip_runtime.h>
#include <stdint.h>

typedef __attribute__((ext_vector_type(4))) float f32x4;
typedef __attribute__((ext_vector_type(8))) short short8;
typedef __attribute__((ext_vector_type(4))) float float4v;
typedef __attribute__((ext_vector_type(2))) unsigned uint2v;

#define GLOAD_LDS16(gsrc, ldst)                                                        \
  __builtin_amdgcn_global_load_lds((const __attribute__((address_space(1))) void*)(gsrc), \
                                   (__attribute__((address_space(3))) void*)(ldst), 16, 0, 0)

// fp32 -> bf16 round-to-nearest-even
static __device__ __forceinline__ short f2bf(float x) {
  unsigned u = __builtin_bit_cast(unsigned, x);
  u = (u + 0x7FFFu + ((u >> 16) & 1u)) >> 16;
  return (short)u;
}

static __device__ __forceinline__ f32x4 mfma16x16x32(short8 a, short8 b, f32x4 c) {
  return __builtin_amdgcn_mfma_f32_16x16x32_bf16(a, b, c, 0, 0, 0);
}

// ---------------- fp32 -> bf16 elementwise convert ----------------
__global__ __launch_bounds__(256) void k_cvt(const float* __restrict__ in,
                                             short* __restrict__ out, int n) {
  int i = (blockIdx.x * 256 + threadIdx.x) * 8;
  if (i >= n) return;
  float4v a = *(const float4v*)(in + i);
  float4v b = *(const float4v*)(in + i + 4);
  short8 r;
  r[0] = f2bf(a[0]); r[1] = f2bf(a[1]); r[2] = f2bf(a[2]); r[3] = f2bf(a[3]);
  r[4] = f2bf(b[0]); r[5] = f2bf(b[1]); r[6] = f2bf(b[2]); r[7] = f2bf(b[3]);
  *(short8*)(out + i) = r;
}

// ---------------- fp32 W (K x N) -> bf16 W^T (N x K), tiled ----------------
__global__ __launch_bounds__(256) void k_transpose(const float* __restrict__ W0, const float* __restrict__ W1,
                                                   const float* __restrict__ W2, const float* __restrict__ W3,
                                                   short* __restrict__ T0, short* __restrict__ T1,
                                                   short* __restrict__ T2, short* __restrict__ T3, int Dm) {
  const float* W = blockIdx.z == 0 ? W0 : blockIdx.z == 1 ? W1 : blockIdx.z == 2 ? W2 : W3;
  short*       T = blockIdx.z == 0 ? T0 : blockIdx.z == 1 ? T1 : blockIdx.z == 2 ? T2 : T3;
  __shared__ float tile[32][33];
  const int tx = threadIdx.x, ty = threadIdx.y;  // 32 x 8
  const int x0 = blockIdx.x * 32, y0 = blockIdx.y * 32;
#pragma unroll
  for (int i = 0; i < 4; i++)
    tile[ty + i * 8][tx] = W[(size_t)(y0 + ty + i * 8) * Dm + x0 + tx];
  __syncthreads();
#pragma unroll
  for (int i = 0; i < 4; i++)
    T[(size_t)(x0 + ty + i * 8) * Dm + y0 + tx] = f2bf(tile[tx][ty + i * 8]);
}

// ---------------- bf16 V (per b,h: key x d) -> V^T (bh, d, key), tiled ----------------
__global__ __launch_bounds__(256) void k_vtr(const short* __restrict__ Vb, short* __restrict__ VtG) {
  __shared__ short tile[32][33];
  const int tx = threadIdx.x, ty = threadIdx.y;  // 32 x 8
  const int bh = blockIdx.z, b = bh >> 4, h = bh & 15;
  const int k0 = blockIdx.x * 32, d0 = blockIdx.y * 32;
#pragma unroll
  for (int i = 0; i < 4; i++)
    tile[ty + i * 8][tx] = Vb[(size_t)(b * 2048 + k0 + ty + i * 8) * 2048 + h * 128 + d0 + tx];
  __syncthreads();
#pragma unroll
  for (int i = 0; i < 4; i++)
    VtG[(size_t)bh * 262144 + (size_t)(d0 + ty + i * 8) * 2048 + k0 + tx] = tile[tx][ty + i * 8];
}

// ---------------- bf16 GEMM 256x128 tile, counted-vmcnt, 3-slot (72KB LDS) ----------------
// C = A(MxK) * Bt(NxK)^T. Block 256x128, BK=32, 4 waves (2Mx2N), wave tile 128x64
// (8x4 frags): 21845 MACs per ds_read_b128 vs 16384 at 64x64 — attacks the LDS-issue
// bound. 2 blocks/CU (72KB LDS, ~190 VGPR). 6 loads/tile, prefetch 2 deep:
// s_waitcnt vmcnt(6) in main loop (tile t drained, t+1 in flight), never 0.
// Output slab-select: col n -> C(n>>11), col n&2047 (fused QKV); Q slab pre-scaled.
template <bool BF16_OUT>
__global__ __launch_bounds__(256, 2) void k_gemm(const short* __restrict__ A, const short* __restrict__ Bt,
                                                 short* __restrict__ C0, short* __restrict__ C1,
                                                 short* __restrict__ C2, float* __restrict__ Cf,
                                                 int M, int K, float qs) {
  __shared__ __align__(16) short As[3][8192];  // 3 slots x 256x32
  __shared__ __align__(16) short Bs[3][4096];  // 3 slots x 128x32
  const int t = threadIdx.x, lane = t & 63, wave = t >> 6;
  const int m0 = blockIdx.x * 256, n0 = blockIdx.y * 128;
  const int wr = wave >> 1, wc = wave & 1;  // wave tile: rows [wr*128,+128), cols [wc*64,+64)
  f32x4 acc[8][4];
#pragma unroll
  for (int m = 0; m < 8; m++)
#pragma unroll
    for (int n = 0; n < 4; n++) acc[m][n] = (f32x4){0.f, 0.f, 0.f, 0.f};

  const int frow = lane & 15, fk = (lane >> 4) * 8;
  const int sr = t >> 2;  // staging row base; col8 = (t&3)*8

#define ISSUE_TILE(TT)                                                                  \
  do {                                                                                  \
    const int s2_ = (TT) % 3;                                                           \
    const size_t kk_ = (size_t)(TT) * 32 + (t & 3) * 8;                                 \
    GLOAD_LDS16(A + (size_t)(m0 + sr) * K + kk_, &As[s2_][t * 8]);                      \
    GLOAD_LDS16(A + (size_t)(m0 + sr + 64) * K + kk_, &As[s2_][t * 8 + 2048]);          \
    GLOAD_LDS16(A + (size_t)(m0 + sr + 128) * K + kk_, &As[s2_][t * 8 + 4096]);         \
    GLOAD_LDS16(A + (size_t)(m0 + sr + 192) * K + kk_, &As[s2_][t * 8 + 6144]);         \
    GLOAD_LDS16(Bt + (size_t)(n0 + sr) * K + kk_, &Bs[s2_][t * 8]);                     \
    GLOAD_LDS16(Bt + (size_t)(n0 + sr + 64) * K + kk_, &Bs[s2_][t * 8 + 2048]);         \
  } while (0)

#define GEMM_BODY(VMLIT, TT, DOISSUE)                                                   \
  do {                                                                                  \
    asm volatile("s_waitcnt vmcnt(" VMLIT ")" ::: "memory");                            \
    __builtin_amdgcn_s_barrier();                                                       \
    __builtin_amdgcn_sched_barrier(0);                                                  \
    if (DOISSUE) ISSUE_TILE((TT) + 2);                                                  \
    const int s_ = (TT) % 3;                                                            \
    short8 af[8], bfr[4];                                                               \
    _Pragma("unroll") for (int m = 0; m < 8; m++)                                       \
        af[m] = *(const short8*)(&As[s_][(wr * 128 + m * 16 + frow) * 32 + fk]);        \
    _Pragma("unroll") for (int n = 0; n < 4; n++)                                       \
        bfr[n] = *(const short8*)(&Bs[s_][(wc * 64 + n * 16 + frow) * 32 + fk]);        \
    _Pragma("unroll") for (int m = 0; m < 8; m++)                                       \
      _Pragma("unroll") for (int n = 0; n < 4; n++)                                     \
          acc[m][n] = mfma16x16x32(af[m], bfr[n], acc[m][n]);                           \
  } while (0)

  const int NTK = K / 32;  // 64
  ISSUE_TILE(0);
  ISSUE_TILE(1);
  int tt = 0;
  for (; tt < NTK - 2; ++tt) GEMM_BODY("6", tt, 1);
  GEMM_BODY("6", tt, 0); ++tt;   // 12 -> 6 outstanding (tile NTK-2 drained)
  GEMM_BODY("0", tt, 0);         // 6 -> 0

#undef GEMM_BODY
#undef ISSUE_TILE

  const int crow = (lane >> 4) * 4, ccol = lane & 15;
  const int slab = n0 >> 11, ncol = n0 & 2047;  // 2048-wide output slabs
  short* Cb = slab == 0 ? C0 : slab == 1 ? C1 : C2;
  const float sc = (BF16_OUT && slab == 0) ? qs : 1.0f;  // pre-scale Q by sl2e (fp32, exact)
#pragma unroll
  for (int m = 0; m < 8; m++)
#pragma unroll
    for (int n = 0; n < 4; n++) {
      const int gr = m0 + wr * 128 + m * 16 + crow;
      const int gc = ncol + wc * 64 + n * 16 + ccol;
#pragma unroll
      for (int r = 0; r < 4; r++) {
        if constexpr (BF16_OUT)
          Cb[(size_t)(gr + r) * 2048 + gc] = f2bf(acc[m][n][r] * sc);
        else
          Cf[(size_t)(gr + r) * 2048 + gc] = acc[m][n][r];
      }
    }
}

// ---------------- flash attention: max-free softmax, swapped QK^T, full-DMA staging ----------------
// (unchanged from R14 — passing at ~87 us, ~790 TF)
__global__ __launch_bounds__(256, 2) void k_attn(const short* __restrict__ Q, const short* __restrict__ K,
                                                 const short* __restrict__ VtG, short* __restrict__ O,
                                                 int T, int Hn) {
  constexpr int HD = 128;
  __shared__ __align__(16) short Ks[2][64 * 128];  // [key][d], swizzled granules (32KB)
  __shared__ __align__(16) short Vs[2][128 * 64];  // [d][key], swizzled granules (32KB)
  __shared__ __align__(16) short Ps[4][32 * 64];   // per-wave [q][key], swizzled (16KB)
  const int t = threadIdx.x, lane = t & 63, wave = t >> 6;
  const int bid = blockIdx.x + gridDim.x * blockIdx.y;  // 0..511
  const int bh = (bid & 7) * 4 + ((bid >> 3) >> 4);     // XCD-grouped (b*16+h) in [0,32)
  const int qb = (bid >> 3) & 15;                       // 0..15
  const int b = bh / Hn, h = bh % Hn;
  const int q0 = qb * 128;
  const int D = Hn * HD;
  const short* Qp = Q + (size_t)b * T * D + h * HD;
  const short* Kp = K + (size_t)b * T * D + h * HD;
  const short* VpT = VtG + (size_t)bh * 262144;  // [d][key], key contiguous
  const int l15 = lane & 15, l4 = lane >> 4;

  short8 qf[2][4];
#pragma unroll
  for (int rg = 0; rg < 2; rg++) {
    const short* qrow = Qp + (size_t)(q0 + wave * 32 + rg * 16 + l15) * D + l4 * 8;
#pragma unroll
    for (int dd = 0; dd < 4; dd++) qf[rg][dd] = *(const short8*)(qrow + dd * 32);
  }
  short8 ones;
#pragma unroll
  for (int j = 0; j < 8; j++) ones[j] = (short)0x3F80;  // bf16 1.0

  f32x4 acc[2][8], lacc[2];
#pragma unroll
  for (int rg = 0; rg < 2; rg++) {
    lacc[rg] = (f32x4){0.f, 0.f, 0.f, 0.f};
#pragma unroll
    for (int i = 0; i < 8; i++) acc[rg][i] = (f32x4){0.f, 0.f, 0.f, 0.f};
  }

  int kRow[4], kC8[4], vD[4], vO[4];
#pragma unroll
  for (int it = 0; it < 4; it++) {
    const int g = it * 256 + t;
    kRow[it] = g >> 4;
    kC8[it] = (g & 15) ^ (kRow[it] & 7);
    vD[it] = g >> 3;
    vO[it] = (g & 7) ^ (vD[it] & 7);
  }

#pragma unroll
  for (int it = 0; it < 4; it++) {
    GLOAD_LDS16(Kp + (size_t)kRow[it] * D + kC8[it] * 8, &Ks[0][(it * 256 + wave * 64) * 8]);
    GLOAD_LDS16(VpT + (size_t)vD[it] * 2048 + vO[it] * 8, &Vs[0][(it * 256 + wave * 64) * 8]);
  }
  __syncthreads();

  const int NT = T / 64;
  for (int tt = 0; tt < NT; tt++) {
    const int cur = tt & 1, nxt = cur ^ 1;

    if (tt + 1 < NT) {
#pragma unroll
      for (int it = 0; it < 4; it++) {
        GLOAD_LDS16(Kp + (size_t)((tt + 1) * 64 + kRow[it]) * D + kC8[it] * 8,
                    &Ks[nxt][(it * 256 + wave * 64) * 8]);
        GLOAD_LDS16(VpT + (size_t)vD[it] * 2048 + (tt + 1) * 64 + vO[it] * 8,
                    &Vs[nxt][(it * 256 + wave * 64) * 8]);
      }
    }

    f32x4 z[2][4];
#pragma unroll
    for (int rg = 0; rg < 2; rg++)
#pragma unroll
      for (int n = 0; n < 4; n++) z[rg][n] = (f32x4){0.f, 0.f, 0.f, 0.f};
#pragma unroll
    for (int dd = 0; dd < 4; dd++) {
#pragma unroll
      for (int n = 0; n < 4; n++) {
        const int krow = n * 16 + l15;
        const int c8p = (dd * 4 + l4) ^ (krow & 7);
        short8 kf = *(const short8*)(&Ks[cur][krow * 128 + c8p * 8]);
        z[0][n] = mfma16x16x32(kf, qf[0][dd], z[0][n]);  // A=K rows, B=Q rows
        z[1][n] = mfma16x16x32(kf, qf[1][dd], z[1][n]);
      }
    }

#pragma unroll
    for (int rg = 0; rg < 2; rg++)
#pragma unroll
      for (int n = 0; n < 4; n++) {
        const unsigned u0 = __builtin_bit_cast(unsigned, exp2f(z[rg][n][0]));
        const unsigned u1 = __builtin_bit_cast(unsigned, exp2f(z[rg][n][1]));
        const unsigned u2 = __builtin_bit_cast(unsigned, exp2f(z[rg][n][2]));
        const unsigned u3 = __builtin_bit_cast(unsigned, exp2f(z[rg][n][3]));
        uint2v w;
        w[0] = (u1 & 0xFFFF0000u) | (u0 >> 16);  // truncating bf16; bias cancels in acc/lacc
        w[1] = (u3 & 0xFFFF0000u) | (u2 >> 16);
        const int row = rg * 16 + l15;
        const int g = (n * 2 + (l4 >> 1)) ^ (l15 & 7);
        *(uint2v*)(&Ps[wave][row * 64 + g * 8 + (l4 & 1) * 4]) = w;
      }
    asm volatile("s_waitcnt lgkmcnt(0)" ::: "memory");
    __builtin_amdgcn_sched_barrier(0);

#pragma unroll
    for (int kk = 0; kk < 2; kk++) {
      short8 pa[2];
#pragma unroll
      for (int rg = 0; rg < 2; rg++) {
        const int row = rg * 16 + l15;
        const int c8p = (kk * 4 + l4) ^ (row & 7);
        pa[rg] = *(const short8*)(&Ps[wave][row * 64 + c8p * 8]);
        lacc[rg] = mfma16x16x32(pa[rg], ones, lacc[rg]);
      }
#pragma unroll
      for (int n8 = 0; n8 < 8; n8++) {
        const int vrow = n8 * 16 + l15;
        const int vc8 = (kk * 4 + l4) ^ (vrow & 7);
        short8 vb = *(const short8*)(&Vs[cur][vrow * 64 + vc8 * 8]);
        acc[0][n8] = mfma16x16x32(pa[0], vb, acc[0][n8]);
        acc[1][n8] = mfma16x16x32(pa[1], vb, acc[1][n8]);
      }
    }

    __syncthreads();  // vmcnt0 (t+1 K/V resident) + lgkm0; protects cur buffers
  }

#pragma unroll
  for (int rg = 0; rg < 2; rg++) {
    float rl[4];
#pragma unroll
    for (int r = 0; r < 4; r++) rl[r] = 1.0f / lacc[rg][r];
#pragma unroll
    for (int n8 = 0; n8 < 8; n8++)
#pragma unroll
      for (int r = 0; r < 4; r++) {
        const int qr = q0 + wave * 32 + rg * 16 + l4 * 4 + r;
        O[(size_t)(b * T + qr) * D + h * HD + n8 * 16 + l15] = f2bf(acc[rg][n8][r] * rl[r]);
      }
  }
}

extern "C" void kernel_launch(void* const* d_in, const int* in_sizes, int n_in,
                              void* d_out, int out_size, void* d_ws, size_t ws_size,
                              hipStream_t stream) {
  const float* hs = (const float*)d_in[0];
  const float* Wq = (const float*)d_in[1];
  const float* Wk = (const float*)d_in[2];
  const float* Wv = (const float*)d_in[3];
  const float* Wo = (const float*)d_in[4];
  // d_in[5] (Wd), d_in[6] (bd): dead code — jnp.maximum(dms, causal) == 0 everywhere.
  float* out = (float*)d_out;

  const int B = 2, T = 2048, D = 2048, H = 16;
  const int M = B * T;
  const float sl2e = 0.1275174385f;  // (1/sqrt(128)) * log2(e)

  short* hsb = (short*)d_ws;                 // M*D bf16 (reused as VtG after QKV GEMM)
  short* WqT = hsb + (size_t)M * D;          // D*D each; WqT|WkT|WvT contiguous => fused B (6144 x 2048)
  short* WkT = WqT + (size_t)D * D;
  short* WvT = WkT + (size_t)D * D;
  short* WoT = WvT + (size_t)D * D;
  short* Qb  = WoT + (size_t)D * D;          // M*D each
  short* Kb  = Qb + (size_t)M * D;
  short* Vb  = Kb + (size_t)M * D;
  short* AOb = Vb + (size_t)M * D;
  short* VtG = hsb;                          // alias: hsb is dead after the QKV GEMM

  k_cvt<<<(M * D) / 2048, 256, 0, stream>>>(hs, hsb, M * D);
  k_transpose<<<dim3(D / 32, D / 32, 4), dim3(32, 8), 0, stream>>>(Wq, Wk, Wv, Wo, WqT, WkT, WvT, WoT, D);
  // fused QKV: C = hsb @ [Wq|Wk|Wv], N = 6144, 256x128 tiles, slab-routed (Q pre-scaled)
  k_gemm<true><<<dim3(M / 256, 3 * D / 128), 256, 0, stream>>>(hsb, WqT, Qb, Kb, Vb, nullptr, M, D, sl2e);
  // V -> V^T per (b,h): [bh][d][key]
  k_vtr<<<dim3(T / 32, 4, B * H), dim3(32, 8), 0, stream>>>(Vb, VtG);
  k_attn<<<dim3(T / 128, B * H), 256, 0, stream>>>(Qb, Kb, VtG, AOb, T, H);
  k_gemm<false><<<dim3(M / 256, D / 128), 256, 0, stream>>>(AOb, WoT, nullptr, nullptr, nullptr, out, M, D, 1.0f);
}

// Round 16
// 286.004 us; speedup vs baseline: 1.2370x; 1.2370x over previous
//
#include <hip/hip_runtime.h>
#include <stdint.h>

typedef __attribute__((ext_vector_type(4))) float f32x4;
typedef __attribute__((ext_vector_type(8))) short short8;
typedef __attribute__((ext_vector_type(4))) float float4v;
typedef __attribute__((ext_vector_type(2))) unsigned uint2v;

#define GLOAD_LDS16(gsrc, ldst)                                                        \
  __builtin_amdgcn_global_load_lds((const __attribute__((address_space(1))) void*)(gsrc), \
                                   (__attribute__((address_space(3))) void*)(ldst), 16, 0, 0)

// fp32 -> bf16 round-to-nearest-even
static __device__ __forceinline__ short f2bf(float x) {
  unsigned u = __builtin_bit_cast(unsigned, x);
  u = (u + 0x7FFFu + ((u >> 16) & 1u)) >> 16;
  return (short)u;
}

static __device__ __forceinline__ f32x4 mfma16x16x32(short8 a, short8 b, f32x4 c) {
  return __builtin_amdgcn_mfma_f32_16x16x32_bf16(a, b, c, 0, 0, 0);
}

// ---------------- fp32 -> bf16 elementwise convert ----------------
__global__ __launch_bounds__(256) void k_cvt(const float* __restrict__ in,
                                             short* __restrict__ out, int n) {
  int i = (blockIdx.x * 256 + threadIdx.x) * 8;
  if (i >= n) return;
  float4v a = *(const float4v*)(in + i);
  float4v b = *(const float4v*)(in + i + 4);
  short8 r;
  r[0] = f2bf(a[0]); r[1] = f2bf(a[1]); r[2] = f2bf(a[2]); r[3] = f2bf(a[3]);
  r[4] = f2bf(b[0]); r[5] = f2bf(b[1]); r[6] = f2bf(b[2]); r[7] = f2bf(b[3]);
  *(short8*)(out + i) = r;
}

// ---------------- fp32 W (K x N) -> bf16 W^T (N x K), tiled ----------------
__global__ __launch_bounds__(256) void k_transpose(const float* __restrict__ W0, const float* __restrict__ W1,
                                                   const float* __restrict__ W2, const float* __restrict__ W3,
                                                   short* __restrict__ T0, short* __restrict__ T1,
                                                   short* __restrict__ T2, short* __restrict__ T3, int Dm) {
  const float* W = blockIdx.z == 0 ? W0 : blockIdx.z == 1 ? W1 : blockIdx.z == 2 ? W2 : W3;
  short*       T = blockIdx.z == 0 ? T0 : blockIdx.z == 1 ? T1 : blockIdx.z == 2 ? T2 : T3;
  __shared__ float tile[32][33];
  const int tx = threadIdx.x, ty = threadIdx.y;  // 32 x 8
  const int x0 = blockIdx.x * 32, y0 = blockIdx.y * 32;
#pragma unroll
  for (int i = 0; i < 4; i++)
    tile[ty + i * 8][tx] = W[(size_t)(y0 + ty + i * 8) * Dm + x0 + tx];
  __syncthreads();
#pragma unroll
  for (int i = 0; i < 4; i++)
    T[(size_t)(x0 + ty + i * 8) * Dm + y0 + tx] = f2bf(tile[tx][ty + i * 8]);
}

// ---------------- bf16 V (per b,h: key x d) -> V^T (bh, d, key), tiled ----------------
__global__ __launch_bounds__(256) void k_vtr(const short* __restrict__ Vb, short* __restrict__ VtG) {
  __shared__ short tile[32][33];
  const int tx = threadIdx.x, ty = threadIdx.y;  // 32 x 8
  const int bh = blockIdx.z, b = bh >> 4, h = bh & 15;
  const int k0 = blockIdx.x * 32, d0 = blockIdx.y * 32;
#pragma unroll
  for (int i = 0; i < 4; i++)
    tile[ty + i * 8][tx] = Vb[(size_t)(b * 2048 + k0 + ty + i * 8) * 2048 + h * 128 + d0 + tx];
  __syncthreads();
#pragma unroll
  for (int i = 0; i < 4; i++)
    VtG[(size_t)bh * 262144 + (size_t)(d0 + ty + i * 8) * 2048 + k0 + tx] = tile[tx][ty + i * 8];
}

// ---------------- bf16 GEMM, counted-vmcnt pipelined, 3-slot, octet-swizzled LDS ----------------
// C(MxN) = A(MxK) * Bt(NxK)^T.  128x128 tile, BK=32, 4 waves (2x2), 3 blocks/CU.
// Counted vmcnt(4) (never 0 in main loop), prefetch 2 ahead.
// LDS bank-conflict fix (rule 21, both-sides involution): rows stride 64B = 16 banks,
// so unswizzled b128 fragment reads are 8-way conflicted. Octet swizzle
// o ^= (row ^ (row>>2)) & 3 applied to BOTH the gload_lds SOURCE octet (content
// permutation; dest stays linear) and the ds_read octet -> 2-way (free, m136).
// On read side f = (frow ^ (frow>>2)) & 3 (m*16, wr*64 drop out mod 16) = per-lane const.
template <bool BF16_OUT>
__global__ __launch_bounds__(256, 3) void k_gemm(const short* __restrict__ A, const short* __restrict__ Bt,
                                                 short* __restrict__ C0, short* __restrict__ C1,
                                                 short* __restrict__ C2, float* __restrict__ Cf,
                                                 int M, int K, float qs) {
  __shared__ __align__(16) short As[3][4096];  // 3 slots x 128x32
  __shared__ __align__(16) short Bs[3][4096];
  const int t = threadIdx.x, lane = t & 63, wave = t >> 6;
  const int m0 = blockIdx.x * 128, n0 = blockIdx.y * 128;
  const int wr = wave >> 1, wc = wave & 1;
  f32x4 acc[4][4];
#pragma unroll
  for (int m = 0; m < 4; m++)
#pragma unroll
    for (int n = 0; n < 4; n++) acc[m][n] = (f32x4){0.f, 0.f, 0.f, 0.f};

  const int frow = lane & 15;
  // read-side swizzled octet offset (elements): (l4 ^ f(row)) * 8, f per-lane const
  const int fk = ((lane >> 4) ^ ((frow ^ (frow >> 2)) & 3)) * 8;
  // staging: granules g0 = wave*128+lane and g0+64; row = g>>2 (and +16), octet = lane&3.
  // f(row) = ((lane>>2) ^ (lane>>4)) & 3 for BOTH granules (row+16 preserves it).
  const int g0 = wave * 128 + lane;
  const int sr0 = g0 >> 2, sr1 = sr0 + 16;
  const int scs = (((lane & 3) ^ (((lane >> 2) ^ (lane >> 4)) & 3)) * 8);  // swizzled src octet

#define ISSUE_TILE(TT)                                                                  \
  do {                                                                                  \
    const int s2_ = (TT) % 3;                                                           \
    const size_t kk_ = (size_t)(TT) * 32 + scs;                                         \
    GLOAD_LDS16(A + (size_t)(m0 + sr0) * K + kk_, &As[s2_][wave * 1024]);               \
    GLOAD_LDS16(Bt + (size_t)(n0 + sr0) * K + kk_, &Bs[s2_][wave * 1024]);              \
    GLOAD_LDS16(A + (size_t)(m0 + sr1) * K + kk_, &As[s2_][wave * 1024 + 512]);         \
    GLOAD_LDS16(Bt + (size_t)(n0 + sr1) * K + kk_, &Bs[s2_][wave * 1024 + 512]);        \
  } while (0)

#define GEMM_BODY(VMLIT, TT, DOISSUE)                                                   \
  do {                                                                                  \
    asm volatile("s_waitcnt vmcnt(" VMLIT ")" ::: "memory");                            \
    __builtin_amdgcn_s_barrier();                                                       \
    __builtin_amdgcn_sched_barrier(0);                                                  \
    if (DOISSUE) ISSUE_TILE((TT) + 2);                                                  \
    const int s_ = (TT) % 3;                                                            \
    short8 af[4], bfr[4];                                                               \
    _Pragma("unroll") for (int m = 0; m < 4; m++)                                       \
        af[m] = *(const short8*)(&As[s_][(wr * 64 + m * 16 + frow) * 32 + fk]);         \
    _Pragma("unroll") for (int n = 0; n < 4; n++)                                       \
        bfr[n] = *(const short8*)(&Bs[s_][(wc * 64 + n * 16 + frow) * 32 + fk]);        \
    _Pragma("unroll") for (int m = 0; m < 4; m++)                                       \
      _Pragma("unroll") for (int n = 0; n < 4; n++)                                     \
          acc[m][n] = mfma16x16x32(af[m], bfr[n], acc[m][n]);                           \
  } while (0)

  const int NTK = K / 32;  // 64
  ISSUE_TILE(0);
  ISSUE_TILE(1);
  int tt = 0;
  for (; tt < NTK - 2; ++tt) GEMM_BODY("4", tt, 1);
  GEMM_BODY("4", tt, 0); ++tt;
  GEMM_BODY("0", tt, 0);

#undef GEMM_BODY
#undef ISSUE_TILE

  const int crow = ((lane >> 4)) * 4, ccol = lane & 15;
  const int slab = n0 >> 11, ncol = n0 & 2047;  // 2048-wide output slabs
  short* Cb = slab == 0 ? C0 : slab == 1 ? C1 : C2;
  const float sc = (BF16_OUT && slab == 0) ? qs : 1.0f;  // pre-scale Q by sl2e (fp32, exact)
#pragma unroll
  for (int m = 0; m < 4; m++)
#pragma unroll
    for (int n = 0; n < 4; n++) {
      const int gr = m0 + wr * 64 + m * 16 + crow;
      const int gc = ncol + wc * 64 + n * 16 + ccol;
#pragma unroll
      for (int r = 0; r < 4; r++) {
        if constexpr (BF16_OUT)
          Cb[(size_t)(gr + r) * 2048 + gc] = f2bf(acc[m][n][r] * sc);
        else
          Cf[(size_t)(gr + r) * 2048 + gc] = acc[m][n][r];
      }
    }
}

// ---------------- flash attention: max-free softmax, swapped QK^T, full-DMA staging ----------------
// (R14-proven: ~87 us, ~790 TF)
__global__ __launch_bounds__(256, 2) void k_attn(const short* __restrict__ Q, const short* __restrict__ K,
                                                 const short* __restrict__ VtG, short* __restrict__ O,
                                                 int T, int Hn) {
  constexpr int HD = 128;
  __shared__ __align__(16) short Ks[2][64 * 128];  // [key][d], swizzled granules (32KB)
  __shared__ __align__(16) short Vs[2][128 * 64];  // [d][key], swizzled granules (32KB)
  __shared__ __align__(16) short Ps[4][32 * 64];   // per-wave [q][key], swizzled (16KB)
  const int t = threadIdx.x, lane = t & 63, wave = t >> 6;
  const int bid = blockIdx.x + gridDim.x * blockIdx.y;  // 0..511
  const int bh = (bid & 7) * 4 + ((bid >> 3) >> 4);     // XCD-grouped (b*16+h) in [0,32)
  const int qb = (bid >> 3) & 15;                       // 0..15
  const int b = bh / Hn, h = bh % Hn;
  const int q0 = qb * 128;
  const int D = Hn * HD;
  const short* Qp = Q + (size_t)b * T * D + h * HD;
  const short* Kp = K + (size_t)b * T * D + h * HD;
  const short* VpT = VtG + (size_t)bh * 262144;  // [d][key], key contiguous
  const int l15 = lane & 15, l4 = lane >> 4;

  short8 qf[2][4];
#pragma unroll
  for (int rg = 0; rg < 2; rg++) {
    const short* qrow = Qp + (size_t)(q0 + wave * 32 + rg * 16 + l15) * D + l4 * 8;
#pragma unroll
    for (int dd = 0; dd < 4; dd++) qf[rg][dd] = *(const short8*)(qrow + dd * 32);
  }
  short8 ones;
#pragma unroll
  for (int j = 0; j < 8; j++) ones[j] = (short)0x3F80;  // bf16 1.0

  f32x4 acc[2][8], lacc[2];
#pragma unroll
  for (int rg = 0; rg < 2; rg++) {
    lacc[rg] = (f32x4){0.f, 0.f, 0.f, 0.f};
#pragma unroll
    for (int i = 0; i < 8; i++) acc[rg][i] = (f32x4){0.f, 0.f, 0.f, 0.f};
  }

  int kRow[4], kC8[4], vD[4], vO[4];
#pragma unroll
  for (int it = 0; it < 4; it++) {
    const int g = it * 256 + t;
    kRow[it] = g >> 4;
    kC8[it] = (g & 15) ^ (kRow[it] & 7);
    vD[it] = g >> 3;
    vO[it] = (g & 7) ^ (vD[it] & 7);
  }

#pragma unroll
  for (int it = 0; it < 4; it++) {
    GLOAD_LDS16(Kp + (size_t)kRow[it] * D + kC8[it] * 8, &Ks[0][(it * 256 + wave * 64) * 8]);
    GLOAD_LDS16(VpT + (size_t)vD[it] * 2048 + vO[it] * 8, &Vs[0][(it * 256 + wave * 64) * 8]);
  }
  __syncthreads();

  const int NT = T / 64;
  for (int tt = 0; tt < NT; tt++) {
    const int cur = tt & 1, nxt = cur ^ 1;

    if (tt + 1 < NT) {
#pragma unroll
      for (int it = 0; it < 4; it++) {
        GLOAD_LDS16(Kp + (size_t)((tt + 1) * 64 + kRow[it]) * D + kC8[it] * 8,
                    &Ks[nxt][(it * 256 + wave * 64) * 8]);
        GLOAD_LDS16(VpT + (size_t)vD[it] * 2048 + (tt + 1) * 64 + vO[it] * 8,
                    &Vs[nxt][(it * 256 + wave * 64) * 8]);
      }
    }

    f32x4 z[2][4];
#pragma unroll
    for (int rg = 0; rg < 2; rg++)
#pragma unroll
      for (int n = 0; n < 4; n++) z[rg][n] = (f32x4){0.f, 0.f, 0.f, 0.f};
#pragma unroll
    for (int dd = 0; dd < 4; dd++) {
#pragma unroll
      for (int n = 0; n < 4; n++) {
        const int krow = n * 16 + l15;
        const int c8p = (dd * 4 + l4) ^ (krow & 7);
        short8 kf = *(const short8*)(&Ks[cur][krow * 128 + c8p * 8]);
        z[0][n] = mfma16x16x32(kf, qf[0][dd], z[0][n]);  // A=K rows, B=Q rows
        z[1][n] = mfma16x16x32(kf, qf[1][dd], z[1][n]);
      }
    }

#pragma unroll
    for (int rg = 0; rg < 2; rg++)
#pragma unroll
      for (int n = 0; n < 4; n++) {
        const unsigned u0 = __builtin_bit_cast(unsigned, exp2f(z[rg][n][0]));
        const unsigned u1 = __builtin_bit_cast(unsigned, exp2f(z[rg][n][1]));
        const unsigned u2 = __builtin_bit_cast(unsigned, exp2f(z[rg][n][2]));
        const unsigned u3 = __builtin_bit_cast(unsigned, exp2f(z[rg][n][3]));
        uint2v w;
        w[0] = (u1 & 0xFFFF0000u) | (u0 >> 16);  // truncating bf16; bias cancels in acc/lacc
        w[1] = (u3 & 0xFFFF0000u) | (u2 >> 16);
        const int row = rg * 16 + l15;
        const int g = (n * 2 + (l4 >> 1)) ^ (l15 & 7);
        *(uint2v*)(&Ps[wave][row * 64 + g * 8 + (l4 & 1) * 4]) = w;
      }
    asm volatile("s_waitcnt lgkmcnt(0)" ::: "memory");
    __builtin_amdgcn_sched_barrier(0);

#pragma unroll
    for (int kk = 0; kk < 2; kk++) {
      short8 pa[2];
#pragma unroll
      for (int rg = 0; rg < 2; rg++) {
        const int row = rg * 16 + l15;
        const int c8p = (kk * 4 + l4) ^ (row & 7);
        pa[rg] = *(const short8*)(&Ps[wave][row * 64 + c8p * 8]);
        lacc[rg] = mfma16x16x32(pa[rg], ones, lacc[rg]);
      }
#pragma unroll
      for (int n8 = 0; n8 < 8; n8++) {
        const int vrow = n8 * 16 + l15;
        const int vc8 = (kk * 4 + l4) ^ (vrow & 7);
        short8 vb = *(const short8*)(&Vs[cur][vrow * 64 + vc8 * 8]);
        acc[0][n8] = mfma16x16x32(pa[0], vb, acc[0][n8]);
        acc[1][n8] = mfma16x16x32(pa[1], vb, acc[1][n8]);
      }
    }

    __syncthreads();  // vmcnt0 (t+1 K/V resident) + lgkm0; protects cur buffers
  }

#pragma unroll
  for (int rg = 0; rg < 2; rg++) {
    float rl[4];
#pragma unroll
    for (int r = 0; r < 4; r++) rl[r] = 1.0f / lacc[rg][r];
#pragma unroll
    for (int n8 = 0; n8 < 8; n8++)
#pragma unroll
      for (int r = 0; r < 4; r++) {
        const int qr = q0 + wave * 32 + rg * 16 + l4 * 4 + r;
        O[(size_t)(b * T + qr) * D + h * HD + n8 * 16 + l15] = f2bf(acc[rg][n8][r] * rl[r]);
      }
  }
}

extern "C" void kernel_launch(void* const* d_in, const int* in_sizes, int n_in,
                              void* d_out, int out_size, void* d_ws, size_t ws_size,
                              hipStream_t stream) {
  const float* hs = (const float*)d_in[0];
  const float* Wq = (const float*)d_in[1];
  const float* Wk = (const float*)d_in[2];
  const float* Wv = (const float*)d_in[3];
  const float* Wo = (const float*)d_in[4];
  // d_in[5] (Wd), d_in[6] (bd): dead code — jnp.maximum(dms, causal) == 0 everywhere.
  float* out = (float*)d_out;

  const int B = 2, T = 2048, D = 2048, H = 16;
  const int M = B * T;
  const float sl2e = 0.1275174385f;  // (1/sqrt(128)) * log2(e)

  short* hsb = (short*)d_ws;                 // M*D bf16 (reused as VtG after QKV GEMM)
  short* WqT = hsb + (size_t)M * D;          // D*D each; WqT|WkT|WvT contiguous => fused B (6144 x 2048)
  short* WkT = WqT + (size_t)D * D;
  short* WvT = WkT + (size_t)D * D;
  short* WoT = WvT + (size_t)D * D;
  short* Qb  = WoT + (size_t)D * D;          // M*D each
  short* Kb  = Qb + (size_t)M * D;
  short* Vb  = Kb + (size_t)M * D;
  short* AOb = Vb + (size_t)M * D;
  short* VtG = hsb;                          // alias: hsb is dead after the QKV GEMM

  k_cvt<<<(M * D) / 2048, 256, 0, stream>>>(hs, hsb, M * D);
  k_transpose<<<dim3(D / 32, D / 32, 4), dim3(32, 8), 0, stream>>>(Wq, Wk, Wv, Wo, WqT, WkT, WvT, WoT, D);
  // fused QKV: C = hsb @ [Wq|Wk|Wv], N = 6144, slab-routed to Qb/Kb/Vb (Q pre-scaled)
  k_gemm<true><<<dim3(M / 128, 3 * D / 128), 256, 0, stream>>>(hsb, WqT, Qb, Kb, Vb, nullptr, M, D, sl2e);
  // V -> V^T per (b,h): [bh][d][key]
  k_vtr<<<dim3(T / 32, 4, B * H), dim3(32, 8), 0, stream>>>(Vb, VtG);
  k_attn<<<dim3(T / 128, B * H), 256, 0, stream>>>(Qb, Kb, VtG, AOb, T, H);
  k_gemm<false><<<dim3(M / 128, D / 128), 256, 0, stream>>>(AOb, WoT, nullptr, nullptr, nullptr, out, M, D, 1.0f);
}